// Round 5
// baseline (145.466 us; speedup 1.0000x reference)
//
#include <hip/hip_runtime.h>
#include <hip/hip_bf16.h>
#include <math.h>

#define THREADS 512
#define WAVES 8
#define NB 16            // batches per block -> M = 144 rows, 9 M-tiles

typedef __attribute__((ext_vector_type(8))) short bf16x8;
typedef __attribute__((ext_vector_type(4))) float f32x4;

__device__ __forceinline__ float leaky(float x){ return x >= 0.f ? x : 0.02f*x; }
__device__ __forceinline__ float fast_tanh(float x){
  float e = __expf(2.f*x);
  return 1.f - 2.f/(e + 1.f);
}

__device__ __forceinline__ unsigned short f2bf(float f){
  union { float f; unsigned u; } v; v.f = f;
  unsigned r = (v.u + 0x7FFFu + ((v.u >> 16) & 1u)) >> 16;
  return (unsigned short)r;
}
__device__ __forceinline__ float bf2f(unsigned short h){
  union { unsigned u; float f; } v; v.u = ((unsigned)h) << 16;
  return v.f;
}
__device__ __forceinline__ unsigned pack2bf(float a, float b){
  float2 t; t.x = a; t.y = b;
  __hip_bfloat162 h = __float22bfloat162_rn(t);
  union { __hip_bfloat162 h; unsigned u; } c; c.h = h;
  return c.u;
}

template<int L2R>
__device__ __forceinline__ unsigned swz(unsigned b){
  if constexpr (L2R < 0) return b;
  else return b ^ (((b >> L2R) & 7u) << 4);
}

__device__ __forceinline__ f32x4 mfma16(bf16x8 a, bf16x8 b, f32x4 c){
  return __builtin_amdgcn_mfma_f32_16x16x32_bf16(a, b, c, 0, 0, 0);
}

// ---- packed weight layout offsets (bf16 elements), 512 per fragment ----
#define WB_C1 0
#define WB_C2 6144
#define WB_C3 12288
#define WB_C4 36864
#define WB_F1 61440
#define WB_F2 69632
#define WB_F3 77824
#define WB_A1 79872
#define WB_A2 81408
#define WB_A3 82432
#define WB_A4 82944
#define WB_A5 83456
#define WP_TOTAL 83968   // elements; *2 = 167936 bytes

__global__ void pack_weights(
    const float* __restrict__ cw1, const float* __restrict__ cw2,
    const float* __restrict__ cw3, const float* __restrict__ cw4,
    const float* __restrict__ fw1, const float* __restrict__ fw2,
    const float* __restrict__ fw3, const float* __restrict__ aw1,
    const float* __restrict__ aw2, const float* __restrict__ aw3,
    const float* __restrict__ aw4, const float* __restrict__ aw5,
    short* __restrict__ wp)
{
  int g = blockIdx.x*256 + threadIdx.x;
  if (g >= WP_TOTAL) return;
  const float* w; int base, l2cp, cinw, cout, KS; bool conv;
  if      (g < WB_C2){ w=cw1; base=WB_C1; l2cp=6; cinw=64;  cout=32;  KS=6;  conv=true; }
  else if (g < WB_C3){ w=cw2; base=WB_C2; l2cp=5; cinw=32;  cout=64;  KS=3;  conv=true; }
  else if (g < WB_C4){ w=cw3; base=WB_C3; l2cp=6; cinw=64;  cout=128; KS=6;  conv=true; }
  else if (g < WB_F1){ w=cw4; base=WB_C4; l2cp=7; cinw=128; cout=64;  KS=12; conv=true; }
  else if (g < WB_F2){ w=fw1; base=WB_F1; l2cp=6; cinw=64;  cout=128; KS=2;  conv=false; }
  else if (g < WB_F3){ w=fw2; base=WB_F2; l2cp=7; cinw=128; cout=64;  KS=4;  conv=false; }
  else if (g < WB_A1){ w=fw3; base=WB_F3; l2cp=6; cinw=64;  cout=32;  KS=2;  conv=false; }
  else if (g < WB_A2){ w=aw1; base=WB_A1; l2cp=5; cinw=32;  cout=16;  KS=3;  conv=true; }
  else if (g < WB_A3){ w=aw2; base=WB_A2; l2cp=4; cinw=16;  cout=8;   KS=2;  conv=true; }
  else if (g < WB_A4){ w=aw3; base=WB_A3; l2cp=3; cinw=8;   cout=4;   KS=1;  conv=true; }
  else if (g < WB_A5){ w=aw4; base=WB_A4; l2cp=3; cinw=4;   cout=2;   KS=1;  conv=true; }
  else               { w=aw5; base=WB_A5; l2cp=3; cinw=2;   cout=1;   KS=1;  conv=true; }
  int local = g - base;
  int frag = local >> 9;
  int lane = (local >> 3) & 63;
  int j    = local & 7;
  int nt = frag / KS, ks = frag - nt*KS;
  int hi = lane >> 4, lo = lane & 15;
  int k = ks*32 + hi*8 + j;
  int n = nt*16 + lo;
  float v = 0.f;
  if (n < cout){
    if (conv){
      int dt = k >> l2cp, ci = k & ((1<<l2cp)-1);
      if (dt < 3 && ci < cinw) v = w[((size_t)n*cinw + ci)*3 + dt];
    } else {
      v = w[(size_t)n*cinw + k];
    }
  }
  wp[g] = (short)f2bf(v);
}

// ---------------- unified MFMA layer (operand-swapped: D[n][R]) ----------------
// MYNT: register-blocked N tiles per wave -> one A-read feeds MYNT MFMAs.
// IN_CONV: input padded conv layout [bl][11][CINP]; else flat [R][K=CINP]
// OUT_MODE: 0 conv-padded [bl][11][STORE_CH] (+pad-zero rows), 1 flat [R][COUT],
//           2 conv4-flat [bl][576] (c*9+t), 3 conv-layout no-pad-loop
// ACT: 0 leaky, 1 tanh
template<int CINP, int CINW, int COUT, int STORE_CH, int KS, int MYNT,
         int L2RI, int L2RO, bool IN_CONV, int OUT_MODE, int ACT,
         int LBASE, bool PACKED>
__device__ __forceinline__ void mfma_layer(
    const short* __restrict__ wp, const float* __restrict__ w,
    const float* __restrict__ bias, const char* __restrict__ inb,
    char* __restrict__ outb, int tid)
{
  constexpr int NT = (COUT + 15)/16;
  constexpr int NTG = (NT + MYNT - 1)/MYNT;  // nt-groups
  constexpr int L2CINP = (CINP==8?3:CINP==16?4:CINP==32?5:CINP==64?6:7);
  const int wave = tid >> 6, lane = tid & 63;
  const int hi = lane >> 4, lo = lane & 15;

  int nt0, mlo, mhi;
  if constexpr (NTG >= WAVES){
    nt0 = (wave % NTG) * MYNT; mlo = 0; mhi = 9;
  } else {
    constexpr int WPN = WAVES/NTG;
    int seg = wave / NTG; int g = wave - seg*NTG;
    nt0 = g*MYNT; mlo = (9*seg)/WPN; mhi = (9*(seg+1))/WPN;
  }

  // B operand = weights (A-role in swapped mfma): lane -> (n = lo, k = hi*8+j)
  bf16x8 Bf[MYNT][KS];
  #pragma unroll
  for (int nt = 0; nt < MYNT; ++nt){
    #pragma unroll
    for (int ks = 0; ks < KS; ++ks){
      if constexpr (PACKED){
        Bf[nt][ks] = *(const bf16x8*)(wp + LBASE + (((nt0+nt)*KS + ks) << 9) + lane*8);
      } else {
        int n = (nt0+nt)*16 + lo;
        #pragma unroll
        for (int j = 0; j < 8; ++j){
          int k = ks*32 + hi*8 + j;
          float v = 0.f;
          if (n < COUT){
            if constexpr (IN_CONV){
              int dt = k >> L2CINP, ci = k & (CINP-1);
              if (dt < 3 && ci < CINW) v = w[((size_t)n*CINW + ci)*3 + dt];
            } else {
              v = w[(size_t)n*CINP + k];
            }
          }
          Bf[nt][ks][j] = (short)f2bf(v);
        }
      }
    }
  }

  // bias: 4 consecutive channels per lane in swapped C-layout
  float bb[MYNT][4];
  #pragma unroll
  for (int nt = 0; nt < MYNT; ++nt){
    #pragma unroll
    for (int r = 0; r < 4; ++r){
      int n = (nt0+nt)*16 + hi*4 + r;
      bb[nt][r] = (n < COUT) ? bias[n] : 0.f;
    }
  }

  const unsigned hi16 = (unsigned)hi * 16u;

  for (int m = mlo; m < mhi; ++m){
    int R = m*16 + lo;
    int bl2 = 0, t2 = 0, ridx = R;
    if constexpr (IN_CONV || OUT_MODE != 1){
      bl2 = R/9; t2 = R - bl2*9; ridx = bl2*11 + t2;
    }
    unsigned base_in;
    if constexpr (IN_CONV) base_in = ((unsigned)ridx << (L2CINP+1));
    else                   base_in = ((unsigned)R    << (L2CINP+1));

    f32x4 acc[MYNT];
    #pragma unroll
    for (int nt = 0; nt < MYNT; ++nt)
      acc[nt] = (f32x4){bb[nt][0], bb[nt][1], bb[nt][2], bb[nt][3]};

    #pragma unroll
    for (int ks = 0; ks < KS; ++ks){
      unsigned byte0 = base_in + (unsigned)(ks*64) + hi16;
      bf16x8 Af = *(const bf16x8*)(inb + swz<L2RI>(byte0));
      #pragma unroll
      for (int nt = 0; nt < MYNT; ++nt)
        acc[nt] = mfma16(Bf[nt][ks], Af, acc[nt]);   // SWAPPED: D[n][R]
    }

    #pragma unroll
    for (int nt = 0; nt < MYNT; ++nt){
      const int n0 = (nt0+nt)*16 + hi*4;
      if constexpr (OUT_MODE == 2){
        #pragma unroll
        for (int r = 0; r < 4; ++r){
          int n = n0 + r;
          float vr = (ACT==0) ? leaky(acc[nt][r]) : fast_tanh(acc[nt][r]);
          unsigned byte = (unsigned)((bl2*576 + n*9 + t2)*2);
          *(short*)(outb + swz<L2RO>(byte)) = (short)f2bf(vr);
        }
      } else if constexpr (STORE_CH == 1){
        if (hi == 0){
          float vr = (ACT==0) ? leaky(acc[nt][0]) : fast_tanh(acc[nt][0]);
          *(short*)(outb + (unsigned)((ridx + 1)*2)) = (short)f2bf(vr);
        }
      } else {
        if (n0 < STORE_CH){
          float v[4];
          #pragma unroll
          for (int r = 0; r < 4; ++r){
            float vr = (ACT==0) ? leaky(acc[nt][r]) : fast_tanh(acc[nt][r]);
            if constexpr (STORE_CH > COUT){ if (n0 + r >= COUT) vr = 0.f; }
            v[r] = vr;
          }
          unsigned rowO = (OUT_MODE == 1) ? (unsigned)R : (unsigned)(ridx + 1);
          unsigned byte = rowO * (unsigned)(STORE_CH*2) + (unsigned)(n0*2);
          uint2 pk; pk.x = pack2bf(v[0], v[1]); pk.y = pack2bf(v[2], v[3]);
          *(uint2*)(outb + swz<L2RO>(byte)) = pk;
        }
      }
    }
  }

  if constexpr (OUT_MODE == 0){
    // zero pad rows (t=0 and t=10) across all STORE_CH channels
    for (int i = tid; i < NB*2*STORE_CH/4; i += THREADS){
      int bl = i / (2*STORE_CH/4); int rem = i - bl*(2*STORE_CH/4);
      int side = rem / (STORE_CH/4); int c4 = rem - side*(STORE_CH/4);
      unsigned byte = (unsigned)(((bl*11 + side*10)*STORE_CH + c4*4)*2);
      uint2 z; z.x = 0u; z.y = 0u;
      *(uint2*)(outb + swz<L2RO>(byte)) = z;
    }
  }
}

// tail buffer offsets within RB
#define A2OFF 5760
#define A3OFF 8704
#define A4OFF 11648
#define A5OFF 14592

template<bool PACKED>
__global__ __launch_bounds__(THREADS, 4)
void fused_expr_kernel(
    const float* __restrict__ x, const int* __restrict__ ident,
    const float* __restrict__ cw1, const float* __restrict__ cb1,
    const float* __restrict__ cw2, const float* __restrict__ cb2,
    const float* __restrict__ cw3, const float* __restrict__ cb3,
    const float* __restrict__ cw4, const float* __restrict__ cb4,
    const float* __restrict__ fw1, const float* __restrict__ fb1,
    const float* __restrict__ fw2, const float* __restrict__ fb2,
    const float* __restrict__ fw3, const float* __restrict__ fb3,
    const float* __restrict__ aw1, const float* __restrict__ ab1,
    const float* __restrict__ aw2, const float* __restrict__ ab2,
    const float* __restrict__ aw3, const float* __restrict__ ab3,
    const float* __restrict__ aw4, const float* __restrict__ ab4,
    const float* __restrict__ aw5, const float* __restrict__ ab5,
    const float* __restrict__ lw,  const float* __restrict__ lb,
    const float* __restrict__ mapping, const short* __restrict__ wp,
    float* __restrict__ out)
{
  __shared__ __align__(16) char pool[67584];
  __shared__ float logits_s[NB*9];
  __shared__ float att_s[NB*9];
  __shared__ float sub_s[NB*32];

  char* RA = pool;            // 45056 bytes
  char* RB = pool + 45056;    // 22528 bytes

  const int tid = threadIdx.x;
  const int b0 = blockIdx.x * NB;
  const int p  = tid >> 4;    // 0..31
  const int bl = tid & 15;

  // ---- stage x (fp32, (B,9,64)) -> RB bf16 [bl][11][64] padded, swz<7>
  {
    const float4* xb4 = (const float4*)(x + (size_t)b0 * 576);
    for (int i = tid; i < NB*144; i += THREADS){
      int b = i / 144; int rem = i - b*144;     // rem = t*16 + c4
      int t = rem >> 4; int c4 = rem & 15;
      float4 v = xb4[i];
      uint2 pk;
      pk.x = pack2bf(v.x, v.y);
      pk.y = pack2bf(v.z, v.w);
      unsigned byte = (unsigned)(((b*11 + t + 1)*64 + c4*4)*2);
      *(uint2*)(RB + swz<7>(byte)) = pk;
    }
    for (int i = tid; i < 512; i += THREADS){
      int b = i >> 5; int rem = i & 31;
      int side = rem >> 4; int c4 = rem & 15;
      unsigned byte = (unsigned)(((b*11 + side*10)*64 + c4*4)*2);
      uint2 z; z.x = 0u; z.y = 0u;
      *(uint2*)(RB + swz<7>(byte)) = z;
    }
  }
  __syncthreads();

  //          CINP CINW COUT  SC  KS MYNT LI LO  CONV  OM ACT
  mfma_layer<64, 64, 32, 32, 6, 2, 7, 6, true, 0, 0, WB_C1, PACKED>(wp, cw1, cb1, RB, RA, tid); __syncthreads();
  mfma_layer<32, 32, 64, 64, 3, 2, 6, 7, true, 0, 0, WB_C2, PACKED>(wp, cw2, cb2, RA, RB, tid); __syncthreads();
  mfma_layer<64, 64,128,128, 6, 2, 7, 8, true, 0, 0, WB_C3, PACKED>(wp, cw3, cb3, RB, RA, tid); __syncthreads();
  mfma_layer<128,128,64, 64,12, 1, 8, 7, true, 2, 0, WB_C4, PACKED>(wp, cw4, cb4, RA, RB, tid); __syncthreads(); // flat [bl][576]
  mfma_layer<64, 64,128,128, 2, 4, 7, 8, false,1, 0, WB_F1, PACKED>(wp, fw1, fb1, RB, RA, tid); __syncthreads(); // flat [R][128]
  mfma_layer<128,128,64, 64, 4, 2, 8, 7, false,1, 0, WB_F2, PACKED>(wp, fw2, fb2, RA, RB, tid); __syncthreads(); // flat [R][64]
  mfma_layer<64, 64, 32, 32, 2, 2, 7, 6, false,0, 1, WB_F3, PACKED>(wp, fw3, fb3, RB, RA, tid); __syncthreads(); // rs [bl][11][32]

  char* rs = RA;               // [bl][11][32] swz6, live until the end
  char* a1 = RB;               // [bl][11][16] swz5, 5632 B
  char* a2 = RB + A2OFF;       // [bl][11][8]  2816 B (no swz)
  char* a3 = RB + A3OFF;       // [bl][11][8]  (4 real ch + zero pad)
  char* a4 = RB + A4OFF;       // [bl][11][8]  (2 real ch + zero pad)
  char* a5 = RB + A5OFF;       // [bl][11][1]  352 B

  mfma_layer<32, 32, 16, 16, 3, 1, 6, 5, true, 0, 0, WB_A1, PACKED>(wp, aw1, ab1, rs, a1, tid); __syncthreads();
  mfma_layer<16, 16,  8,  8, 2, 1, 5,-1, true, 0, 0, WB_A2, PACKED>(wp, aw2, ab2, a1, a2, tid); __syncthreads();
  mfma_layer< 8,  8,  4,  8, 1, 1,-1,-1, true, 0, 0, WB_A3, PACKED>(wp, aw3, ab3, a2, a3, tid); __syncthreads();
  mfma_layer< 8,  4,  2,  8, 1, 1,-1,-1, true, 0, 0, WB_A4, PACKED>(wp, aw4, ab4, a3, a4, tid); __syncthreads();
  mfma_layer< 8,  2,  1,  1, 1, 1,-1,-1, true, 3, 0, WB_A5, PACKED>(wp, aw5, ab5, a4, a5, tid); __syncthreads();

  // logits[b][o] = lb[o] + sum_t a5[b][t] * lw[o][t]
  if (p < 9){
    float acc = lb[p];
    #pragma unroll
    for (int t = 0; t < 9; ++t)
      acc = fmaf(lw[p*9 + t], bf2f(*(const unsigned short*)(a5 + (bl*11 + t + 1)*2)), acc);
    logits_s[bl*9 + p] = acc;
  }
  __syncthreads();

  if (p == 0){
    float m = -1e30f;
    #pragma unroll
    for (int t = 0; t < 9; ++t) m = fmaxf(m, logits_s[bl*9 + t]);
    float s = 0.f, ex[9];
    #pragma unroll
    for (int t = 0; t < 9; ++t){ ex[t] = __expf(logits_s[bl*9 + t] - m); s += ex[t]; }
    float inv = 1.f / s;
    #pragma unroll
    for (int t = 0; t < 9; ++t) att_s[bl*9 + t] = ex[t]*inv;
  }
  __syncthreads();

  // sub[b][s] = sum_t rs[b][s][t] * att[b][t]
  {
    int s = p;
    float acc = 0.f;
    #pragma unroll
    for (int t = 0; t < 9; ++t){
      unsigned byte = (unsigned)(((bl*11 + t + 1)*32 + s)*2);
      acc = fmaf(bf2f(*(const unsigned short*)(rs + swz<6>(byte))), att_s[bl*9 + t], acc);
    }
    sub_s[bl*32 + s] = acc;
  }
  __syncthreads();

  // out[b][e] = 10 * sum_s mapping[id[b]][e][s] * sub[b][s]
  {
    const int b = b0 + bl;
    const size_t id = (size_t)ident[b];
    const float* mb = mapping + id*53*32;
    float subv[32];
    #pragma unroll
    for (int s = 0; s < 32; ++s) subv[s] = sub_s[bl*32 + s];
    for (int e = p; e < 53; e += 32){
      const float4* mrow4 = (const float4*)(mb + e*32);
      float acc = 0.f;
      #pragma unroll
      for (int s4 = 0; s4 < 8; ++s4){
        float4 mv = mrow4[s4];
        acc = fmaf(mv.x, subv[s4*4+0], acc);
        acc = fmaf(mv.y, subv[s4*4+1], acc);
        acc = fmaf(mv.z, subv[s4*4+2], acc);
        acc = fmaf(mv.w, subv[s4*4+3], acc);
      }
      out[(size_t)b*53 + e] = 10.f*acc;
    }
  }
}

extern "C" void kernel_launch(void* const* d_in, const int* in_sizes, int n_in,
                              void* d_out, int out_size, void* d_ws, size_t ws_size,
                              hipStream_t stream) {
  const float* x    = (const float*)d_in[0];
  const int*   ident= (const int*)  d_in[1];
  const float* cw1  = (const float*)d_in[2];  const float* cb1 = (const float*)d_in[3];
  const float* cw2  = (const float*)d_in[4];  const float* cb2 = (const float*)d_in[5];
  const float* cw3  = (const float*)d_in[6];  const float* cb3 = (const float*)d_in[7];
  const float* cw4  = (const float*)d_in[8];  const float* cb4 = (const float*)d_in[9];
  const float* fw1  = (const float*)d_in[10]; const float* fb1 = (const float*)d_in[11];
  const float* fw2  = (const float*)d_in[12]; const float* fb2 = (const float*)d_in[13];
  const float* fw3  = (const float*)d_in[14]; const float* fb3 = (const float*)d_in[15];
  const float* aw1  = (const float*)d_in[16]; const float* ab1 = (const float*)d_in[17];
  const float* aw2  = (const float*)d_in[18]; const float* ab2 = (const float*)d_in[19];
  const float* aw3  = (const float*)d_in[20]; const float* ab3 = (const float*)d_in[21];
  const float* aw4  = (const float*)d_in[22]; const float* ab4 = (const float*)d_in[23];
  const float* aw5  = (const float*)d_in[24]; const float* ab5 = (const float*)d_in[25];
  const float* lw   = (const float*)d_in[26]; const float* lb  = (const float*)d_in[27];
  const float* mapping = (const float*)d_in[28];

  const int B = 32768;
  dim3 grid(B / NB), block(THREADS);

  const bool packed = ws_size >= (size_t)(WP_TOTAL * 2);
  short* wpk = (short*)d_ws;

  if (packed){
    pack_weights<<<dim3(WP_TOTAL/256), dim3(256), 0, stream>>>(
        cw1, cw2, cw3, cw4, fw1, fw2, fw3, aw1, aw2, aw3, aw4, aw5, wpk);
    fused_expr_kernel<true><<<grid, block, 0, stream>>>(
        x, ident, cw1, cb1, cw2, cb2, cw3, cb3, cw4, cb4,
        fw1, fb1, fw2, fb2, fw3, fb3,
        aw1, ab1, aw2, ab2, aw3, ab3, aw4, ab4, aw5, ab5,
        lw, lb, mapping, wpk, (float*)d_out);
  } else {
    fused_expr_kernel<false><<<grid, block, 0, stream>>>(
        x, ident, cw1, cb1, cw2, cb2, cw3, cb3, cw4, cb4,
        fw1, fb1, fw2, fb2, fw3, fb3,
        aw1, ab1, aw2, ab2, aw3, ab3, aw4, ab4, aw5, ab5,
        lw, lb, mapping, wpk, (float*)d_out);
  }
}